// Round 4
// baseline (321.363 us; speedup 1.0000x reference)
//
#include <hip/hip_runtime.h>

#define BS   32
#define SLEN 4096
#define EM   256
#define NROWS (BS * SLEN)  // 131072

typedef __attribute__((ext_vector_type(8))) short bf16x8;
typedef __attribute__((ext_vector_type(4))) float f32x4;

// ---------------- ws layout (floats) ----------------
#define WS_WKB   0         // 32768  : wk as bf16 [e][j]
#define WS_EN    32768     // 131072 : raw energy (tanh(k)@we_k)
#define WS_CONST 163840    // 16     : scalar energy_q + be
#define WS_W     163856    // 131072 : softmax weights
#define WS_PART  294928    // 262144 : wsum partials (32b x 32ch) x 256
// total 557072 floats = 2.23 MB

__device__ inline short f2bf(float x) {
  union { float f; unsigned u; } v; v.f = x;
  unsigned r = v.u + 0x7fffu + ((v.u >> 16) & 1u);  // RNE
  return (short)(r >> 16);
}

// branch-free tanh for x >= 0 (post-relu). e2=inf -> 1 - 2/inf = 1 (no NaN).
__device__ inline float tanh_pos(float x) {
  float e2 = __expf(2.f * x);
  return 1.f - __fdividef(2.f, e2 + 1.f);
}

// ---- K0: convert wk (fp32 [e][j]) -> bf16 [e][j] ----
__global__ __launch_bounds__(256) void k0_cvt(const float* __restrict__ wk,
                                              unsigned short* __restrict__ wkb) {
  int idx = (blockIdx.x * 256 + threadIdx.x) * 4;
  float4 v = *(const float4*)(wk + idx);
  ushort4 o;
  o.x = (unsigned short)f2bf(v.x);
  o.y = (unsigned short)f2bf(v.y);
  o.z = (unsigned short)f2bf(v.z);
  o.w = (unsigned short)f2bf(v.w);
  *(ushort4*)(wkb + idx) = o;
}

// ---- K0b: scalar query path: C = tanh(relu(wq@w_query+bq)) . we_q + be ----
__global__ __launch_bounds__(256) void k0b_qscalar(const float* __restrict__ w_query,
                                                   const float* __restrict__ wq,
                                                   const float* __restrict__ bq,
                                                   const float* __restrict__ we,
                                                   const float* __restrict__ be,
                                                   float* __restrict__ outc) {
  int t = threadIdx.x;  // t = e
  float a = 0.f;
  const float* row = wq + (size_t)t * EM;
#pragma unroll 8
  for (int j = 0; j < EM; ++j) a = fmaf(row[j], w_query[j], a);
  a += bq[t];
  float v = we[t] * tanh_pos(fmaxf(a, 0.f));
#pragma unroll
  for (int off = 32; off >= 1; off >>= 1) v += __shfl_xor(v, off, 64);
  __shared__ float red[4];
  if ((t & 63) == 0) red[t >> 6] = v;
  __syncthreads();
  if (t == 0) outc[0] = red[0] + red[1] + red[2] + red[3] + be[0];
}

// ---- K1 (MFMA, no-LDS): energy[row] = sum_e we_k[e]*tanh(relu((X@wkT)[r][e]+bk[e]))
// Block 256 thr = 4 waves, NO barriers in K-loop. Wave (wr,wc) owns
// rows blk*64 + wr*32 + [0,32) x cols wc*128 + [0,128).
// A fragment = 8 contiguous k-floats of one X row -> direct global load + cvt.
// B fragment = 8 contiguous k-bf16 of one wkb row -> direct global load (L2-hot).
__global__ __launch_bounds__(256) void k1_energy(const float* __restrict__ X,
                                                 const unsigned short* __restrict__ wkb,
                                                 const float* __restrict__ bk,
                                                 const float* __restrict__ we,
                                                 float* __restrict__ energy) {
  __shared__ float ep[64][2];
  const int tid = threadIdx.x;
  const int l = tid & 63;
  const int wid = tid >> 6;
  const int wr = wid >> 1, wc = wid & 1;
  const int lr = l & 15, lk = l >> 4;
  const int row0 = blockIdx.x * 64;
  const float* xw = X + (size_t)(row0 + wr * 32 + lr) * EM;          // +i*16*EM +k
  const unsigned short* bw = wkb + (size_t)(wc * 128 + lr) * EM;     // +n*16*EM +k

  f32x4 acc[2][8];
#pragma unroll
  for (int i = 0; i < 2; ++i)
#pragma unroll
    for (int n = 0; n < 8; ++n) acc[i][n] = (f32x4){0.f, 0.f, 0.f, 0.f};

#pragma unroll
  for (int s = 0; s < 8; ++s) {
    const int kf = s * 32 + lk * 8;
    bf16x8 af[2];
#pragma unroll
    for (int i = 0; i < 2; ++i) {
      const float* src = xw + (size_t)(i * 16) * EM + kf;
      float4 v0 = *(const float4*)src;
      float4 v1 = *(const float4*)(src + 4);
      bf16x8 t;
      t[0] = f2bf(v0.x); t[1] = f2bf(v0.y); t[2] = f2bf(v0.z); t[3] = f2bf(v0.w);
      t[4] = f2bf(v1.x); t[5] = f2bf(v1.y); t[6] = f2bf(v1.z); t[7] = f2bf(v1.w);
      af[i] = t;
    }
    bf16x8 bfr[8];
#pragma unroll
    for (int n = 0; n < 8; ++n)
      bfr[n] = *(const bf16x8*)(bw + (size_t)(n * 16) * EM + kf);
#pragma unroll
    for (int i = 0; i < 2; ++i)
#pragma unroll
      for (int n = 0; n < 8; ++n)
        acc[i][n] = __builtin_amdgcn_mfma_f32_16x16x32_bf16(af[i], bfr[n], acc[i][n], 0, 0, 0);
  }

  // ---- fused epilogue (fp32): bias, relu, tanh, dot we_k, row-reduce ----
  float bkv[8], wev[8];
#pragma unroll
  for (int n = 0; n < 8; ++n) {
    int e = wc * 128 + n * 16 + lr;
    bkv[n] = bk[e];
    wev[n] = we[EM + e];
  }
#pragma unroll
  for (int i = 0; i < 2; ++i) {
#pragma unroll
    for (int r = 0; r < 4; ++r) {
      float p = 0.f;
#pragma unroll
      for (int n = 0; n < 8; ++n) {
        float kv = fmaxf(acc[i][n][r] + bkv[n], 0.f);
        p += wev[n] * tanh_pos(kv);
      }
#pragma unroll
      for (int off = 1; off <= 8; off <<= 1) p += __shfl_xor(p, off, 64);
      if (lr == 0) ep[wr * 32 + i * 16 + lk * 4 + r][wc] = p;
    }
  }
  __syncthreads();
  if (tid < 64) energy[row0 + tid] = ep[tid][0] + ep[tid][1];
}

// ---- K2: per-batch masked softmax over SLEN (byte-vs-int32 mask probe) ----
__global__ __launch_bounds__(256) void k2_softmax(const float* __restrict__ energy,
                                                  const unsigned char* __restrict__ mask,
                                                  const float* __restrict__ cptr,
                                                  float* __restrict__ wout) {
  const int b = blockIdx.x;
  const int t = threadIdx.x;
  const float C = cptr[0];
  const bool mask_is_byte = (mask[1] | mask[2] | mask[3]) != 0;
  const int* mask32 = (const int*)mask;
  const float* eb = energy + (size_t)b * SLEN;
  float v[16];
  float m = -3.4e38f;
#pragma unroll
  for (int i = 0; i < 16; ++i) {
    int s = t + i * 256;
    int mv = mask_is_byte ? (int)mask[(size_t)b * SLEN + s]
                          : mask32[(size_t)b * SLEN + s];
    float x = mv ? (eb[s] + C) : 1.4012984643248171e-45f;
    v[i] = x;
    m = fmaxf(m, x);
  }
  __shared__ float red[8];
#pragma unroll
  for (int off = 32; off >= 1; off >>= 1) m = fmaxf(m, __shfl_xor(m, off, 64));
  if ((t & 63) == 0) red[t >> 6] = m;
  __syncthreads();
  m = fmaxf(fmaxf(red[0], red[1]), fmaxf(red[2], red[3]));
  float s_ = 0.f;
#pragma unroll
  for (int i = 0; i < 16; ++i) {
    v[i] = __expf(v[i] - m);
    s_ += v[i];
  }
#pragma unroll
  for (int off = 32; off >= 1; off >>= 1) s_ += __shfl_xor(s_, off, 64);
  if ((t & 63) == 0) red[4 + (t >> 6)] = s_;
  __syncthreads();
  float inv = 1.f / (red[4] + red[5] + red[6] + red[7]);
  float* wb = wout + (size_t)b * SLEN;
#pragma unroll
  for (int i = 0; i < 16; ++i) wb[t + i * 256] = v[i] * inv;
}

// ---- K3: partial weighted sums. grid = 32 b x 32 chunks(128 s); LDS-reduced ----
__global__ __launch_bounds__(256) void k3_wsum(const float* __restrict__ X,
                                               const float* __restrict__ w,
                                               float* __restrict__ part) {
  __shared__ float red[4][EM];
  const int b = blockIdx.x >> 5;
  const int ch = blockIdx.x & 31;
  const int g = threadIdx.x >> 6;   // 0..3 (s sub-group)
  const int l = threadIdx.x & 63;   // float4 slot over EM
  const int s0 = ch * 128 + g * 32;
  const float* xb = X + (size_t)b * SLEN * EM;
  const float* wb = w + (size_t)b * SLEN;
  float4 acc = make_float4(0.f, 0.f, 0.f, 0.f);
#pragma unroll 4
  for (int i = 0; i < 32; ++i) {
    int s = s0 + i;
    float ws_ = wb[s];
    float4 v = *(const float4*)(xb + (size_t)s * EM + l * 4);
    acc.x = fmaf(ws_, v.x, acc.x);
    acc.y = fmaf(ws_, v.y, acc.y);
    acc.z = fmaf(ws_, v.z, acc.z);
    acc.w = fmaf(ws_, v.w, acc.w);
  }
  *(float4*)(&red[g][l * 4]) = acc;
  __syncthreads();
  if (g == 0) {
    float4 r0 = *(const float4*)(&red[0][l * 4]);
    float4 r1 = *(const float4*)(&red[1][l * 4]);
    float4 r2 = *(const float4*)(&red[2][l * 4]);
    float4 r3 = *(const float4*)(&red[3][l * 4]);
    float4 o;
    o.x = (r0.x + r1.x) + (r2.x + r3.x);
    o.y = (r0.y + r1.y) + (r2.y + r3.y);
    o.z = (r0.z + r1.z) + (r2.z + r3.z);
    o.w = (r0.w + r1.w) + (r2.w + r3.w);
    *(float4*)(part + (size_t)(b * 32 + ch) * EM + l * 4) = o;
  }
}

// ---- K4: reduce 32 partials per (b,e) -> out ----
__global__ __launch_bounds__(256) void k4_reduce(const float* __restrict__ part,
                                                 float* __restrict__ out) {
  const int b = blockIdx.x;
  const int e = threadIdx.x;
  float s = 0.f;
#pragma unroll 8
  for (int k = 0; k < 32; ++k) s += part[((size_t)b * 32 + k) * EM + e];
  out[(size_t)b * EM + e] = s;
}

extern "C" void kernel_launch(void* const* d_in, const int* in_sizes, int n_in,
                              void* d_out, int out_size, void* d_ws, size_t ws_size,
                              hipStream_t stream) {
  const float* X = (const float*)d_in[0];
  const unsigned char* mask = (const unsigned char*)d_in[1];
  const float* w_query = (const float*)d_in[2];
  const float* wq = (const float*)d_in[3];
  const float* bq = (const float*)d_in[4];
  const float* wk = (const float*)d_in[5];
  const float* bk = (const float*)d_in[6];
  const float* we = (const float*)d_in[7];
  const float* be = (const float*)d_in[8];
  float* out = (float*)d_out;
  float* ws = (float*)d_ws;

  unsigned short* wkb = (unsigned short*)(ws + WS_WKB);
  float* energy = ws + WS_EN;
  float* cscalar = ws + WS_CONST;
  float* weights = ws + WS_W;
  float* part = ws + WS_PART;

  k0_cvt<<<64, 256, 0, stream>>>(wk, wkb);
  k0b_qscalar<<<1, 256, 0, stream>>>(w_query, wq, bq, we, be, cscalar);
  k1_energy<<<NROWS / 64, 256, 0, stream>>>(X, wkb, bk, we, energy);
  k2_softmax<<<BS, 256, 0, stream>>>(energy, mask, cscalar, weights);
  k3_wsum<<<BS * 32, 256, 0, stream>>>(X, weights, part);
  k4_reduce<<<BS, 256, 0, stream>>>(part, out);
}

// Round 6
// 271.777 us; speedup vs baseline: 1.1824x; 1.1824x over previous
//
#include <hip/hip_runtime.h>

#define BS   32
#define SLEN 4096
#define EM   256
#define NROWS (BS * SLEN)  // 131072

typedef __attribute__((ext_vector_type(8))) short bf16x8;
typedef __attribute__((ext_vector_type(4))) float f32x4;

// ---------------- ws layout (floats) ----------------
#define WS_WKB   0         // 32768  : wk bf16, fragment-major [kq][e][8]
#define WS_EN    32768     // 131072 : raw energy
#define WS_CONST 163840    // 16     : scalar energy_q + be
#define WS_W     163856    // 131072 : softmax weights
#define WS_PART  294928    // 524288 : wsum partials (32b x 64ch) x 256

__device__ inline short f2bf(float x) {
  union { float f; unsigned u; } v; v.f = x;
  unsigned r = v.u + 0x7fffu + ((v.u >> 16) & 1u);  // RNE
  return (short)(r >> 16);
}

#define GLOAD_LDS16(g, l)                                                  \
  __builtin_amdgcn_global_load_lds(                                        \
      (const __attribute__((address_space(1))) unsigned int*)(g),          \
      (__attribute__((address_space(3))) unsigned int*)(l), 16, 0, 0)

// ---- K0: wk fp32 [e][k] -> bf16 fragment-major: chunk16B index kq*256+e,
// kq = k/8 (0..31). So LDS tile for k-step s (32 k) is bytes [s*16K, +16K) linear.
__global__ __launch_bounds__(256) void k0_cvt(const float* __restrict__ wk,
                                              unsigned short* __restrict__ wkb2) {
  int gid = blockIdx.x * 256 + threadIdx.x;  // 8192
  int e = gid >> 5, kq = gid & 31;
  const float* src = wk + (size_t)e * EM + kq * 8;
  float4 v0 = *(const float4*)src;
  float4 v1 = *(const float4*)(src + 4);
  bf16x8 pk;
  pk[0] = f2bf(v0.x); pk[1] = f2bf(v0.y); pk[2] = f2bf(v0.z); pk[3] = f2bf(v0.w);
  pk[4] = f2bf(v1.x); pk[5] = f2bf(v1.y); pk[6] = f2bf(v1.z); pk[7] = f2bf(v1.w);
  *(bf16x8*)(wkb2 + ((size_t)kq * 256 + e) * 8) = pk;
}

// ---- K0b: scalar query path ----
__global__ __launch_bounds__(256) void k0b_qscalar(const float* __restrict__ w_query,
                                                   const float* __restrict__ wq,
                                                   const float* __restrict__ bq,
                                                   const float* __restrict__ we,
                                                   const float* __restrict__ be,
                                                   float* __restrict__ outc) {
  int t = threadIdx.x;  // t = e
  const float* row = wq + (size_t)t * EM;
  float4 a4 = make_float4(0.f, 0.f, 0.f, 0.f);
#pragma unroll 8
  for (int j = 0; j < 64; ++j) {
    float4 r = *(const float4*)(row + j * 4);
    float4 q = *(const float4*)(w_query + j * 4);
    a4.x = fmaf(r.x, q.x, a4.x);
    a4.y = fmaf(r.y, q.y, a4.y);
    a4.z = fmaf(r.z, q.z, a4.z);
    a4.w = fmaf(r.w, q.w, a4.w);
  }
  float a = (a4.x + a4.y) + (a4.z + a4.w) + bq[t];
  float kv = fmaxf(a, 0.f);
  float z = __expf(kv + kv);
  float v = we[t] * (1.f - __fdividef(2.f, z + 1.f));
#pragma unroll
  for (int off = 32; off >= 1; off >>= 1) v += __shfl_xor(v, off, 64);
  __shared__ float red[4];
  if ((t & 63) == 0) red[t >> 6] = v;
  __syncthreads();
  if (t == 0) outc[0] = red[0] + red[1] + red[2] + red[3] + be[0];
}

// ---- K1 (MFMA, dbuf, 1 barrier/iter) ----
// 256 thr = 4 waves (wr=wid>>1 rows wr*32+[0,32), wc=wid&1 cols wc*128+[0,128)).
// Tile 64 rows x 256 cols, BK=32, 8 iters. acc C-init = bk (bias free).
// As[2][64 rows][64B] swizzled chunk^(r&3); Bs[2][16KB] fragment-major linear
// (gload_lds from pre-packed wkb2). Stage t+1 issued BEFORE compute t.
__global__ __launch_bounds__(256) void k1_energy(const float* __restrict__ X,
                                                 const unsigned short* __restrict__ wkb2,
                                                 const float* __restrict__ bk,
                                                 const float* __restrict__ we,
                                                 float* __restrict__ energy) {
  __shared__ char lds[41472];
  char* As = lds;            // 2 x 4096
  char* Bs = lds + 8192;     // 2 x 16384
  float* ep = (float*)(lds + 40960);  // [64][2]
  const int tid = threadIdx.x;
  const int l = tid & 63;
  const int wid = tid >> 6;
  const int wr = wid >> 1, wc = wid & 1;
  const int lr = l & 15, lk = l >> 4;
  const int row0 = blockIdx.x * 64;
  const int ar = tid >> 2, ac = tid & 3;  // A-stage: row, k-chunk(8 floats)

  float bkv[8], wev[8];
#pragma unroll
  for (int n = 0; n < 8; ++n) {
    int e = wc * 128 + n * 16 + lr;
    bkv[n] = bk[e];
    wev[n] = we[EM + e];
  }
  f32x4 acc[2][8];
#pragma unroll
  for (int i = 0; i < 2; ++i)
#pragma unroll
    for (int n = 0; n < 8; ++n)
      acc[i][n] = (f32x4){bkv[n], bkv[n], bkv[n], bkv[n]};

  // ---- prologue: stage tile 0 into buf 0 ----
#pragma unroll
  for (int q = 0; q < 4; ++q) {
    const char* g = (const char*)wkb2 + wid * 4096 + q * 1024 + l * 16;
    GLOAD_LDS16(g, Bs + wid * 4096 + q * 1024);
  }
  {
    const float* src = X + (size_t)(row0 + ar) * EM + ac * 8;
    float4 a0 = *(const float4*)src;
    float4 a1 = *(const float4*)(src + 4);
    bf16x8 pk;
    pk[0] = f2bf(a0.x); pk[1] = f2bf(a0.y); pk[2] = f2bf(a0.z); pk[3] = f2bf(a0.w);
    pk[4] = f2bf(a1.x); pk[5] = f2bf(a1.y); pk[6] = f2bf(a1.z); pk[7] = f2bf(a1.w);
    *(bf16x8*)(As + ar * 64 + ((ac ^ (ar & 3)) * 16)) = pk;
  }
  __syncthreads();

#pragma unroll
  for (int t = 0; t < 8; ++t) {
    const int cur = t & 1, nxt = cur ^ 1;
    float4 a0, a1;
    if (t < 7) {
#pragma unroll
      for (int q = 0; q < 4; ++q) {
        const char* g = (const char*)wkb2 + (t + 1) * 16384 + wid * 4096 + q * 1024 + l * 16;
        GLOAD_LDS16(g, Bs + nxt * 16384 + wid * 4096 + q * 1024);
      }
      const float* src = X + (size_t)(row0 + ar) * EM + (t + 1) * 32 + ac * 8;
      a0 = *(const float4*)src;
      a1 = *(const float4*)(src + 4);
    }
    // compute current buffer
    bf16x8 af[2], bfr[8];
#pragma unroll
    for (int i = 0; i < 2; ++i) {
      int row = wr * 32 + i * 16 + lr;
      af[i] = *(const bf16x8*)(As + cur * 4096 + row * 64 + ((lk ^ (row & 3)) * 16));
    }
#pragma unroll
    for (int n = 0; n < 8; ++n)
      bfr[n] = *(const bf16x8*)(Bs + cur * 16384 + lk * 4096 + (wc * 128 + n * 16 + lr) * 16);
#pragma unroll
    for (int i = 0; i < 2; ++i)
#pragma unroll
      for (int n = 0; n < 8; ++n)
        acc[i][n] = __builtin_amdgcn_mfma_f32_16x16x32_bf16(af[i], bfr[n], acc[i][n], 0, 0, 0);
    if (t < 7) {
      bf16x8 pk;
      pk[0] = f2bf(a0.x); pk[1] = f2bf(a0.y); pk[2] = f2bf(a0.z); pk[3] = f2bf(a0.w);
      pk[4] = f2bf(a1.x); pk[5] = f2bf(a1.y); pk[6] = f2bf(a1.z); pk[7] = f2bf(a1.w);
      *(bf16x8*)(As + nxt * 4096 + ar * 64 + ((ac ^ (ar & 3)) * 16)) = pk;
    }
    __syncthreads();
  }

  // ---- epilogue: relu+tanh+dot(we_k) via p = sumw - 2*sum(we*r), r=1/(1+e^2x)
  float sumw = 0.f, w2[8];
#pragma unroll
  for (int n = 0; n < 8; ++n) { sumw += wev[n]; w2[n] = -2.f * wev[n]; }
#pragma unroll
  for (int i = 0; i < 2; ++i) {
#pragma unroll
    for (int r = 0; r < 4; ++r) {
      float p = sumw;
#pragma unroll
      for (int n = 0; n < 8; ++n) {
        float kv = fmaxf(acc[i][n][r], 0.f);
        float z = __expf(kv + kv);
        float rn = __fdividef(1.f, z + 1.f);
        p = fmaf(w2[n], rn, p);
      }
#pragma unroll
      for (int off = 1; off <= 8; off <<= 1) p += __shfl_xor(p, off, 64);
      if (lr == 0) ep[(wr * 32 + i * 16 + lk * 4 + r) * 2 + wc] = p;
    }
  }
  __syncthreads();
  if (tid < 64) energy[row0 + tid] = ep[tid * 2] + ep[tid * 2 + 1];
}

// ---- K2: per-batch masked softmax over SLEN (byte-vs-int32 mask probe) ----
__global__ __launch_bounds__(256) void k2_softmax(const float* __restrict__ energy,
                                                  const unsigned char* __restrict__ mask,
                                                  const float* __restrict__ cptr,
                                                  float* __restrict__ wout) {
  const int b = blockIdx.x;
  const int t = threadIdx.x;
  const float C = cptr[0];
  const bool mask_is_byte = (mask[1] | mask[2] | mask[3]) != 0;
  const int* mask32 = (const int*)mask;
  const float* eb = energy + (size_t)b * SLEN;
  float v[16];
  float m = -3.4e38f;
#pragma unroll
  for (int i = 0; i < 16; ++i) {
    int s = t + i * 256;
    int mv = mask_is_byte ? (int)mask[(size_t)b * SLEN + s]
                          : mask32[(size_t)b * SLEN + s];
    float x = mv ? (eb[s] + C) : 1.4012984643248171e-45f;
    v[i] = x;
    m = fmaxf(m, x);
  }
  __shared__ float red[8];
#pragma unroll
  for (int off = 32; off >= 1; off >>= 1) m = fmaxf(m, __shfl_xor(m, off, 64));
  if ((t & 63) == 0) red[t >> 6] = m;
  __syncthreads();
  m = fmaxf(fmaxf(red[0], red[1]), fmaxf(red[2], red[3]));
  float s_ = 0.f;
#pragma unroll
  for (int i = 0; i < 16; ++i) {
    v[i] = __expf(v[i] - m);
    s_ += v[i];
  }
#pragma unroll
  for (int off = 32; off >= 1; off >>= 1) s_ += __shfl_xor(s_, off, 64);
  if ((t & 63) == 0) red[4 + (t >> 6)] = s_;
  __syncthreads();
  float inv = 1.f / (red[4] + red[5] + red[6] + red[7]);
  float* wb = wout + (size_t)b * SLEN;
#pragma unroll
  for (int i = 0; i < 16; ++i) wb[t + i * 256] = v[i] * inv;
}

// ---- K3: partial weighted sums. 2048 blocks = 32b x 64ch(64 s each).
// 4 groups x 16 unrolled independent float4 loads per thread -> deep MLP.
__global__ __launch_bounds__(256) void k3_wsum(const float* __restrict__ X,
                                               const float* __restrict__ w,
                                               float* __restrict__ part) {
  __shared__ float red[4][EM];
  const int b = blockIdx.x >> 6;
  const int ch = blockIdx.x & 63;
  const int g = threadIdx.x >> 6;
  const int l = threadIdx.x & 63;
  const int s0 = ch * 64 + g * 16;
  const float* xb = X + (size_t)b * SLEN * EM;
  const float* wb = w + (size_t)b * SLEN;
  float4 acc = make_float4(0.f, 0.f, 0.f, 0.f);
#pragma unroll
  for (int i = 0; i < 16; ++i) {
    int s = s0 + i;
    float ws_ = wb[s];
    float4 v = *(const float4*)(xb + (size_t)s * EM + l * 4);
    acc.x = fmaf(ws_, v.x, acc.x);
    acc.y = fmaf(ws_, v.y, acc.y);
    acc.z = fmaf(ws_, v.z, acc.z);
    acc.w = fmaf(ws_, v.w, acc.w);
  }
  *(float4*)(&red[g][l * 4]) = acc;
  __syncthreads();
  if (g == 0) {
    float4 r0 = *(const float4*)(&red[0][l * 4]);
    float4 r1 = *(const float4*)(&red[1][l * 4]);
    float4 r2 = *(const float4*)(&red[2][l * 4]);
    float4 r3 = *(const float4*)(&red[3][l * 4]);
    float4 o;
    o.x = (r0.x + r1.x) + (r2.x + r3.x);
    o.y = (r0.y + r1.y) + (r2.y + r3.y);
    o.z = (r0.z + r1.z) + (r2.z + r3.z);
    o.w = (r0.w + r1.w) + (r2.w + r3.w);
    *(float4*)(part + (size_t)blockIdx.x * EM + l * 4) = o;
  }
}

// ---- K4: reduce 64 partials per (b,e) -> out ----
__global__ __launch_bounds__(256) void k4_reduce(const float* __restrict__ part,
                                                 float* __restrict__ out) {
  const int b = blockIdx.x;
  const int e = threadIdx.x;
  float s = 0.f;
#pragma unroll 8
  for (int k = 0; k < 64; ++k) s += part[((size_t)b * 64 + k) * EM + e];
  out[(size_t)b * EM + e] = s;
}

extern "C" void kernel_launch(void* const* d_in, const int* in_sizes, int n_in,
                              void* d_out, int out_size, void* d_ws, size_t ws_size,
                              hipStream_t stream) {
  const float* X = (const float*)d_in[0];
  const unsigned char* mask = (const unsigned char*)d_in[1];
  const float* w_query = (const float*)d_in[2];
  const float* wq = (const float*)d_in[3];
  const float* bq = (const float*)d_in[4];
  const float* wk = (const float*)d_in[5];
  const float* bk = (const float*)d_in[6];
  const float* we = (const float*)d_in[7];
  const float* be = (const float*)d_in[8];
  float* out = (float*)d_out;
  float* ws = (float*)d_ws;

  unsigned short* wkb2 = (unsigned short*)(ws + WS_WKB);
  float* energy = ws + WS_EN;
  float* cscalar = ws + WS_CONST;
  float* weights = ws + WS_W;
  float* part = ws + WS_PART;

  k0_cvt<<<32, 256, 0, stream>>>(wk, wkb2);
  k0b_qscalar<<<1, 256, 0, stream>>>(w_query, wq, bq, we, be, cscalar);
  k1_energy<<<NROWS / 64, 256, 0, stream>>>(X, wkb2, bk, we, energy);
  k2_softmax<<<BS, 256, 0, stream>>>(energy, mask, cscalar, weights);
  k3_wsum<<<BS * 64, 256, 0, stream>>>(X, weights, part);
  k4_reduce<<<BS, 256, 0, stream>>>(part, out);
}